// Round 1
// baseline (382.820 us; speedup 1.0000x reference)
//
#include <hip/hip_runtime.h>
#include <hip/hip_bf16.h>

typedef __attribute__((ext_vector_type(8))) short short8;
typedef __attribute__((ext_vector_type(8))) __bf16 bf16x8;
typedef __attribute__((ext_vector_type(4))) float f32x4;

#define N_   4096
#define CQD  128
#define CVD  1024
#define PLD  136   // 128 + 8 pad: 272B row stride -> 2-way max bank aliasing (free)

static __device__ __forceinline__ unsigned short f2bf(float f) {
    union { float f; unsigned int u; } cv; cv.f = f;
    unsigned int u = cv.u;
    u += 0x7fffu + ((u >> 16) & 1u);   // RNE
    return (unsigned short)(u >> 16);
}

static __device__ __forceinline__ f32x4 mfma16(bf16x8 a, bf16x8 b, f32x4 c) {
    return __builtin_amdgcn_mfma_f32_16x16x32_bf16(a, b, c, 0, 0, 0);
}

// ---------------------------------------------------------------------------
// proj: x2d (B,64,H,W,16) -> Qb[b][n][c'], Kb[b][m][c'] (bf16, c' contig),
//       PVcm[b][c'][m] (bf16, m contig).  c'_qk = cq*16+d, c'_v = c*16+d.
// grid 512 (= 2 batches * 256 n-tiles of 16), block 256.
// thread: n = t&15 (within tile), dd = t>>4 (= d).
// ---------------------------------------------------------------------------
__global__ __launch_bounds__(256) void proj_kernel(
    const float* __restrict__ x2d,
    const float* __restrict__ Wq, const float* __restrict__ bq,
    const float* __restrict__ Wk, const float* __restrict__ bk,
    const float* __restrict__ Wv, const float* __restrict__ bv,
    unsigned short* __restrict__ Qb, unsigned short* __restrict__ Kb,
    unsigned short* __restrict__ PV)
{
    const int t  = threadIdx.x;
    const int blk = blockIdx.x;
    const int b  = blk >> 8;
    const int n0 = (blk & 255) << 4;
    const int n  = t & 15;
    const int dd = t >> 4;

    // cache the x column (64 channels) in registers
    const float* xb = x2d + ((size_t)b * 64 * N_ + (size_t)(n0 + n)) * 16 + dd;
    float xr[64];
#pragma unroll
    for (int c = 0; c < 64; ++c) xr[c] = xb[(size_t)c * (N_ * 16)];

    unsigned short* pvb = PV + (size_t)b * CVD * N_;
    for (int j = 0; j < 64; ++j) {          // V rows (c_out = j)
        float acc = bv[j];
#pragma unroll
        for (int c = 0; c < 64; ++c) acc += Wv[j * 64 + c] * xr[c];
        pvb[(size_t)(j * 16 + dd) * N_ + n0 + n] = f2bf(acc);
    }
    unsigned short* qb = Qb + (size_t)b * N_ * CQD;
    unsigned short* kb = Kb + (size_t)b * N_ * CQD;
    for (int j = 0; j < 8; ++j) {           // Q/K rows (cq = j)
        float aq = bq[j], ak = bk[j];
#pragma unroll
        for (int c = 0; c < 64; ++c) {
            float xv = xr[c];
            aq += Wq[j * 64 + c] * xv;
            ak += Wk[j * 64 + c] * xv;
        }
        qb[(size_t)(n0 + n) * CQD + j * 16 + dd] = f2bf(aq);
        kb[(size_t)(n0 + n) * CQD + j * 16 + dd] = f2bf(ak);
    }
}

// ---------------------------------------------------------------------------
// attn: per block (batch, c-half of 512, n-tile of 64), 8 waves / 512 thr.
// m-loop (step 128): waves jointly build p = exp(QK^T) tile (64 x 128) in LDS
// (dbuf), then each wave GEMMs p against its 64-wide PV c-slice.
// Unnormalized accumulation + rowsum; divide + gamma*O + x3d in epilogue.
// ---------------------------------------------------------------------------
__global__ __launch_bounds__(512, 2) void attn_kernel(
    const unsigned short* __restrict__ Qb, const unsigned short* __restrict__ Kb,
    const unsigned short* __restrict__ PV,
    const float* __restrict__ x3d, const float* __restrict__ gamma_p,
    float* __restrict__ outp)
{
    __shared__ unsigned short p_lds[2][64][PLD];
    __shared__ float red[64];

    const int t  = threadIdx.x;
    const int w  = t >> 6;
    const int l  = t & 63;
    const int lo = l & 15;
    const int hi = l >> 4;

    // XCD-aware decode: blocks sharing (batch, c-half) land on 2 dedicated XCDs
    const int id    = blockIdx.x;          // 0..255, XCD = id % 8 (heuristic)
    const int combo = (id >> 1) & 3;
    const int chalf = combo & 1;
    const int b     = combo >> 1;
    const int xl    = ((id >> 3) << 1) | (id & 1);   // n-tile 0..63 (bijective)
    const int n0    = xl << 6;
    const int cw    = (chalf << 9) + (w << 6);       // wave's c' base
    const int g     = w >> 2;                        // n-group (rows g*32..+32) for E
    const int msel  = w & 3;                         // 32-wide m-subchunk for E

    const unsigned short* qp  = Qb + (size_t)b * N_ * CQD;
    const unsigned short* kp  = Kb + (size_t)b * N_ * CQD;
    const unsigned short* pvp = PV + (size_t)b * CVD * N_;

    // Q A-frags for this wave's E rows, held in regs (32 VGPRs)
    bf16x8 qf[2][4];
#pragma unroll
    for (int ns = 0; ns < 2; ++ns)
#pragma unroll
        for (int kk = 0; kk < 4; ++kk)
            qf[ns][kk] = *reinterpret_cast<const bf16x8*>(
                qp + (size_t)(n0 + g * 32 + ns * 16 + lo) * CQD + kk * 32 + hi * 8);

    f32x4 acc[4][4];
#pragma unroll
    for (int i = 0; i < 4; ++i)
#pragma unroll
        for (int j = 0; j < 4; ++j) acc[i][j] = (f32x4){0.f, 0.f, 0.f, 0.f};
    float rs[8];
#pragma unroll
    for (int i = 0; i < 8; ++i) rs[i] = 0.f;

    if (t < 64) red[t] = 0.f;

    for (int it = 0; it < 32; ++it) {
        const int m0  = it << 7;
        const int buf = it & 1;
        const int mc  = m0 + (msel << 5);

        // ---- E phase: this wave's 32n x 32m chunk ----
        bf16x8 kf[2][4];
#pragma unroll
        for (int ms = 0; ms < 2; ++ms)
#pragma unroll
            for (int kk = 0; kk < 4; ++kk)
                kf[ms][kk] = *reinterpret_cast<const bf16x8*>(
                    kp + (size_t)(mc + ms * 16 + lo) * CQD + kk * 32 + hi * 8);
        f32x4 e[2][2];
#pragma unroll
        for (int ns = 0; ns < 2; ++ns)
#pragma unroll
            for (int ms = 0; ms < 2; ++ms) {
                f32x4 ee = (f32x4){0.f, 0.f, 0.f, 0.f};
#pragma unroll
                for (int kk = 0; kk < 4; ++kk) ee = mfma16(qf[ns][kk], kf[ms][kk], ee);
                e[ns][ms] = ee;
            }
        // exp -> rowsum partials + stage p (bf16) to LDS
#pragma unroll
        for (int ns = 0; ns < 2; ++ns)
#pragma unroll
            for (int ms = 0; ms < 2; ++ms)
#pragma unroll
                for (int r = 0; r < 4; ++r) {
                    float p = __expf(e[ns][ms][r]);
                    rs[ns * 4 + r] += p;
                    p_lds[buf][g * 32 + ns * 16 + hi * 4 + r][(msel << 5) + ms * 16 + lo] = f2bf(p);
                }
        __syncthreads();   // one barrier/iter; dbuf makes write-after-read safe

        // ---- PV phase: p (64 x 128) @ PV^T (128 x 64 c-slice) ----
#pragma unroll
        for (int kk = 0; kk < 4; ++kk) {
            bf16x8 af[4];
#pragma unroll
            for (int ns = 0; ns < 4; ++ns)
                af[ns] = *reinterpret_cast<const bf16x8*>(&p_lds[buf][ns * 16 + lo][kk * 32 + hi * 8]);
            bf16x8 bvv[4];
#pragma unroll
            for (int cs = 0; cs < 4; ++cs)
                bvv[cs] = *reinterpret_cast<const bf16x8*>(
                    pvp + (size_t)(cw + cs * 16 + lo) * N_ + m0 + kk * 32 + hi * 8);
#pragma unroll
            for (int ns = 0; ns < 4; ++ns)
#pragma unroll
                for (int cs = 0; cs < 4; ++cs)
                    acc[ns][cs] = mfma16(af[ns], bvv[cs], acc[ns][cs]);
        }
    }

    // ---- rowsum reduction: 16 lanes sharing `hi` hold different m columns ----
#pragma unroll
    for (int i = 0; i < 8; ++i) {
        float v = rs[i];
        v += __shfl_xor(v, 1);
        v += __shfl_xor(v, 2);
        v += __shfl_xor(v, 4);
        v += __shfl_xor(v, 8);
        rs[i] = v;
    }
    if (lo == 0) {
#pragma unroll
        for (int ns = 0; ns < 2; ++ns)
#pragma unroll
            for (int r = 0; r < 4; ++r)
                atomicAdd(&red[g * 32 + ns * 16 + hi * 4 + r], rs[ns * 4 + r]);
    }
    __syncthreads();

    // ---- epilogue: out = gamma * O / rowsum + x3d ----
    const float gmv = gamma_p[0];
    const float* x3p = x3d + (size_t)b * 64 * N_ * 16;
    float* op        = outp + (size_t)b * 64 * N_ * 16;
#pragma unroll
    for (int ns = 0; ns < 4; ++ns) {
        float rinv[4];
#pragma unroll
        for (int r = 0; r < 4; ++r) rinv[r] = 1.0f / red[ns * 16 + hi * 4 + r];
#pragma unroll
        for (int cs = 0; cs < 4; ++cs) {
            const int cp = cw + cs * 16 + lo;
            const size_t base = (size_t)(cp >> 4) * (N_ * 16) + (size_t)(cp & 15);
#pragma unroll
            for (int r = 0; r < 4; ++r) {
                const size_t idx = base + (size_t)(n0 + ns * 16 + hi * 4 + r) * 16;
                op[idx] = gmv * acc[ns][cs][r] * rinv[r] + x3p[idx];
            }
        }
    }
}

extern "C" void kernel_launch(void* const* d_in, const int* in_sizes, int n_in,
                              void* d_out, int out_size, void* d_ws, size_t ws_size,
                              hipStream_t stream)
{
    const float* x2d = (const float*)d_in[0];
    const float* x3d = (const float*)d_in[1];
    const float* Wq  = (const float*)d_in[2];
    const float* bq  = (const float*)d_in[3];
    const float* Wk  = (const float*)d_in[4];
    const float* bk  = (const float*)d_in[5];
    const float* Wv  = (const float*)d_in[6];
    const float* bv  = (const float*)d_in[7];
    const float* gm  = (const float*)d_in[8];

    char* ws = (char*)d_ws;
    unsigned short* Qb = (unsigned short*)ws;                    // 2 MiB
    unsigned short* Kb = (unsigned short*)(ws + (2u << 20));     // 2 MiB
    unsigned short* PV = (unsigned short*)(ws + (4u << 20));     // 16 MiB

    proj_kernel<<<512, 256, 0, stream>>>(x2d, Wq, bq, Wk, bk, Wv, bv, Qb, Kb, PV);
    attn_kernel<<<256, 512, 0, stream>>>(Qb, Kb, PV, x3d, gm, (float*)d_out);
}